// Round 2
// baseline (1540.255 us; speedup 1.0000x reference)
//
#include <hip/hip_runtime.h>
#include <math.h>

#define NN 100000
#define NE 3200000
#define H  32

__device__ __forceinline__ float psi_f(float t) {
    // sign(t) * log1p(|t|)
    return copysignf(log1pf(fabsf(t)), t);
}

__global__ __launch_bounds__(256) void edge_kernel(
    const float* __restrict__ x,
    const int* __restrict__ ei,          // int32! harness converts int64 -> int32
    const float* __restrict__ W1,
    const float* __restrict__ bn_g, const float* __restrict__ bn_b,
    const float* __restrict__ bn_m, const float* __restrict__ bn_v,
    const float* __restrict__ W2, const float* __restrict__ b2,
    const float* __restrict__ W3, const float* __restrict__ b3,
    const float* __restrict__ W4, const float* __restrict__ W5,
    const float* __restrict__ b5,
    float* __restrict__ m_out,
    float* __restrict__ sums, float* __restrict__ counts)
{
    __shared__ __align__(16) float sW2T[H * H];  // sW2T[k*32+c] = W2[c][k]
    __shared__ __align__(16) float sW3T[H * H];  // sW3T[k*32+c] = W3[c][k]
    __shared__ float sA[H], sB[H], sC[H], sB2[H], sB3[H], sW4[H], sW5[H];
    __shared__ float sb5;

    const int tid = threadIdx.x;
    for (int idx = tid; idx < H * H; idx += blockDim.x) {
        int c = idx >> 5, k = idx & 31;           // idx = c*32 + k
        sW2T[k * H + c] = W2[idx];
        sW3T[k * H + c] = W3[idx];
    }
    if (tid < H) {
        float sc = bn_g[tid] * rsqrtf(bn_v[tid] + 1e-5f);
        sA[tid]  = W1[tid] * sc;          // W1[0][c] * scale
        sB[tid]  = W1[H + tid] * sc;      // W1[1][c] * scale
        sC[tid]  = bn_b[tid] - bn_m[tid] * sc;
        sB2[tid] = b2[tid];
        sB3[tid] = b3[tid];
        sW4[tid] = W4[tid];
        sW5[tid] = W5[tid];
    }
    if (tid == 0) sb5 = b5[0];
    __syncthreads();

    for (int e = blockIdx.x * blockDim.x + tid; e < NE;
         e += gridDim.x * blockDim.x) {
        int i = ei[e];
        int j = ei[NE + e];
        float xi0 = x[3 * i], xi1 = x[3 * i + 1], xi2 = x[3 * i + 2];
        float xj0 = x[3 * j], xj1 = x[3 * j + 1], xj2 = x[3 * j + 2];
        float dx = xi0 - xj0, dy = xi1 - xj1, dz = xi2 - xj2;
        float nsq = dx * dx + dy * dy + dz * dz;
        float dot = xi0 * xj0 + xi1 * xj1 + xi2 * xj2;
        float nrm = log1pf(nsq);          // nsq >= 0, so psi == log1p
        float dts = psi_f(dot);

        // phi_e layer 1 (BN folded): h1[c] = relu(nrm*A + dts*B + C)
        float h1[H];
        #pragma unroll
        for (int c = 0; c < H; c++)
            h1[c] = fmaxf(fmaf(nrm, sA[c], fmaf(dts, sB[c], sC[c])), 0.f);

        // phi_e layer 2: h2 = relu(h1 @ W2 + b2)
        float h2[H];
        #pragma unroll
        for (int k = 0; k < H; k++) {
            float acc = sB2[k];
            const float4* w = (const float4*)&sW2T[k * H];
            #pragma unroll
            for (int c4 = 0; c4 < H / 4; c4++) {
                float4 wv = w[c4];
                acc = fmaf(h1[4 * c4 + 0], wv.x, acc);
                acc = fmaf(h1[4 * c4 + 1], wv.y, acc);
                acc = fmaf(h1[4 * c4 + 2], wv.z, acc);
                acc = fmaf(h1[4 * c4 + 3], wv.w, acc);
            }
            h2[k] = fmaxf(acc, 0.f);
        }

        // gate: w = sigmoid(h2 @ W5 + b5); m = h2 * w
        float z = sb5;
        #pragma unroll
        for (int c = 0; c < H; c++) z = fmaf(h2[c], sW5[c], z);
        float wgt = 1.f / (1.f + __expf(-z));
        #pragma unroll
        for (int c = 0; c < H; c++) h2[c] *= wgt;   // h2 now holds m

        // store m (8x float4, contiguous 128B per edge)
        float4* mo = (float4*)(m_out + (size_t)e * H);
        #pragma unroll
        for (int q = 0; q < H / 4; q++)
            mo[q] = make_float4(h2[4 * q], h2[4 * q + 1], h2[4 * q + 2], h2[4 * q + 3]);

        // phi_x: phix = relu(m @ W3 + b3) @ W4
        float phix = 0.f;
        #pragma unroll
        for (int k = 0; k < H; k++) {
            float acc = sB3[k];
            const float4* w = (const float4*)&sW3T[k * H];
            #pragma unroll
            for (int c4 = 0; c4 < H / 4; c4++) {
                float4 wv = w[c4];
                acc = fmaf(h2[4 * c4 + 0], wv.x, acc);
                acc = fmaf(h2[4 * c4 + 1], wv.y, acc);
                acc = fmaf(h2[4 * c4 + 2], wv.z, acc);
                acc = fmaf(h2[4 * c4 + 3], wv.w, acc);
            }
            phix = fmaf(fmaxf(acc, 0.f), sW4[k], phix);
        }

        float ux = fminf(fmaxf(dx * phix, -100.f), 100.f);
        float uy = fminf(fmaxf(dy * phix, -100.f), 100.f);
        float uz = fminf(fmaxf(dz * phix, -100.f), 100.f);
        atomicAdd(&sums[3 * i + 0], ux);
        atomicAdd(&sums[3 * i + 1], uy);
        atomicAdd(&sums[3 * i + 2], uz);
        atomicAdd(&counts[i], 1.f);
    }
}

__global__ __launch_bounds__(256) void node_kernel(
    const float* __restrict__ x,
    const float* __restrict__ sums,
    const float* __restrict__ counts,
    float* __restrict__ out)
{
    int n = blockIdx.x * blockDim.x + threadIdx.x;
    if (n < NN) {
        float inv = 1.f / fmaxf(counts[n], 1.f);
        out[3 * n + 0] = x[3 * n + 0] + sums[3 * n + 0] * inv;
        out[3 * n + 1] = x[3 * n + 1] + sums[3 * n + 1] * inv;
        out[3 * n + 2] = x[3 * n + 2] + sums[3 * n + 2] * inv;
    }
}

extern "C" void kernel_launch(void* const* d_in, const int* in_sizes, int n_in,
                              void* d_out, int out_size, void* d_ws, size_t ws_size,
                              hipStream_t stream) {
    const float* x    = (const float*)d_in[0];
    const int*   ei   = (const int*)d_in[1];     // int32 per harness conversion
    const float* W1   = (const float*)d_in[2];
    const float* bn_g = (const float*)d_in[3];
    const float* bn_b = (const float*)d_in[4];
    const float* bn_m = (const float*)d_in[5];
    const float* bn_v = (const float*)d_in[6];
    const float* W2   = (const float*)d_in[7];
    const float* b2   = (const float*)d_in[8];
    const float* W3   = (const float*)d_in[9];
    const float* b3   = (const float*)d_in[10];
    const float* W4   = (const float*)d_in[11];
    const float* W5   = (const float*)d_in[12];
    const float* b5   = (const float*)d_in[13];

    float* out   = (float*)d_out;        // [x_tilde (3*NN) | m (NE*32)]
    float* m_out = out + (size_t)3 * NN;
    float* sums   = (float*)d_ws;        // [3*NN]
    float* counts = sums + (size_t)3 * NN; // [NN]

    hipMemsetAsync(d_ws, 0, (size_t)4 * NN * sizeof(float), stream);

    edge_kernel<<<(NE + 255) / 256, 256, 0, stream>>>(
        x, ei, W1, bn_g, bn_b, bn_m, bn_v, W2, b2, W3, b3, W4, W5, b5,
        m_out, sums, counts);

    node_kernel<<<(NN + 255) / 256, 256, 0, stream>>>(x, sums, counts, out);
}

// Round 3
// 1013.616 us; speedup vs baseline: 1.5196x; 1.5196x over previous
//
#include <hip/hip_runtime.h>
#include <hip/hip_bf16.h>
#include <math.h>

#define NN 100000
#define NE 3200000
#define H  32
#define NTILES (NE / 32)          // 100000 exact
#define EDGE_BLOCKS 3125          // 3125*4 waves = 12500 -> 8 tiles/wave

typedef __attribute__((ext_vector_type(8)))  short bf8;   // 8 bf16 in 4 VGPRs
typedef __attribute__((ext_vector_type(16))) float f16x;  // MFMA 32x32 acc

__device__ __forceinline__ short f2bf(float f) {
    union { float f; unsigned u; } v; v.f = f;
    unsigned r = (v.u + 0x7FFFu + ((v.u >> 16) & 1u)) >> 16;  // RNE
    return (short)r;
}

// C-layout [16 f32, lane holds col=edge] -> B-operand frags [k=channel][n=edge]
// for the NEXT mfma (K=32 split in two K=16 chunks). Only a half-wave pair
// swap is needed: rows 4-7,20-23 live in the partner lane (lane^32).
__device__ __forceinline__ void cswap(const float* v, int half, bf8& B0, bf8& B1) {
    #pragma unroll
    for (int q = 0; q < 4; q++) {
        float t0 = half ? v[q]      : v[4 + q];
        float r0 = __shfl_xor(t0, 32);
        float a  = half ? r0        : v[q];        // B0[k = 8*half+q]
        float b  = half ? v[4 + q]  : r0;          // B0[k = 8*half+4+q]
        B0[q]     = f2bf(a);
        B0[4 + q] = f2bf(b);
        float t1 = half ? v[8 + q]  : v[12 + q];
        float r1 = __shfl_xor(t1, 32);
        float c  = half ? r1        : v[8 + q];    // B1[k = 16+8*half+q]
        float d  = half ? v[12 + q] : r1;
        B1[q]     = f2bf(c);
        B1[4 + q] = f2bf(d);
    }
}

__global__ __launch_bounds__(256) void edge_kernel(
    const float* __restrict__ x,
    const int* __restrict__ ei,
    const float* __restrict__ W1,
    const float* __restrict__ bn_g, const float* __restrict__ bn_b,
    const float* __restrict__ bn_m, const float* __restrict__ bn_v,
    const float* __restrict__ W2, const float* __restrict__ b2,
    const float* __restrict__ W3, const float* __restrict__ b3,
    const float* __restrict__ W4, const float* __restrict__ W5,
    const float* __restrict__ b5,
    float* __restrict__ m_out,
    float* __restrict__ sums, float* __restrict__ counts)
{
    // per-wave staging region: 32 edges x 32 ch, edge stride 36 f32 (16B-aligned,
    // +4 pad de-phases banks). 4 waves/block.
    __shared__ float smem[4 * 32 * 36];
    const int tid  = threadIdx.x;
    const int lane = tid & 63;
    const int n    = lane & 31;   // edge slot within tile == MFMA col
    const int half = lane >> 5;
    float* lds = &smem[(tid >> 6) * (32 * 36)];

    // ---- stationary per-lane constants (loaded once per wave) ----
    // C/D row set for this lane: row(q) = (q&3) + 8*(q>>2) + 4*half
    float Cf[16], b2c[16], b3c[16], W5c[16], W4c[16];
    #pragma unroll
    for (int q = 0; q < 16; q++) {
        int r = (q & 3) + 8 * (q >> 2) + 4 * half;
        float s = bn_g[r] * rsqrtf(bn_v[r] + 1e-5f);
        Cf[q]  = bn_b[r] - bn_m[r] * s;   // folded BN offset
        b2c[q] = b2[r];
        b3c[q] = b3[r];
        W5c[q] = W5[r];
        W4c[q] = W4[r];
    }
    const float b5v = b5[0];

    // A-operand weights (stationary): A[m=out=n][k], lane k-range = 8*half+j
    // Layer1: A[m][0]=W1[0][m]*sc, A[m][1]=W1[1][m]*sc, rest 0 (single K=16 call)
    bf8 W1a, W2a0, W2a1, W3a0, W3a1;
    #pragma unroll
    for (int q = 0; q < 8; q++) W1a[q] = 0;
    {
        float sc_n = bn_g[n] * rsqrtf(bn_v[n] + 1e-5f);
        if (half == 0) {
            W1a[0] = f2bf(W1[n] * sc_n);
            W1a[1] = f2bf(W1[H + n] * sc_n);
        }
    }
    #pragma unroll
    for (int j = 0; j < 8; j++) {
        int k0 = 8 * half + j;
        W2a0[j] = f2bf(W2[k0 * H + n]);
        W2a1[j] = f2bf(W2[(k0 + 16) * H + n]);
        W3a0[j] = f2bf(W3[k0 * H + n]);
        W3a1[j] = f2bf(W3[(k0 + 16) * H + n]);
    }

    const int wid = blockIdx.x * 4 + (tid >> 6);
    for (int tile = wid; tile < NTILES; tile += gridDim.x * 4) {
        const int e = tile * 32 + n;            // both halves handle same edge
        const int i  = ei[e];
        const int jn = ei[NE + e];
        float xi0 = x[3 * i],  xi1 = x[3 * i + 1],  xi2 = x[3 * i + 2];
        float xj0 = x[3 * jn], xj1 = x[3 * jn + 1], xj2 = x[3 * jn + 2];
        float dx = xi0 - xj0, dy = xi1 - xj1, dz = xi2 - xj2;
        float nsq = dx * dx + dy * dy + dz * dz;
        float dot = xi0 * xj0 + xi1 * xj1 + xi2 * xj2;
        float nrm = log1pf(nsq);
        float dts = copysignf(log1pf(fabsf(dot)), dot);

        // B frag for layer 1: B[0][n]=nrm, B[1][n]=dts, rest 0
        bf8 ndf;
        #pragma unroll
        for (int q = 0; q < 8; q++) ndf[q] = 0;
        if (half == 0) { ndf[0] = f2bf(nrm); ndf[1] = f2bf(dts); }

        // ---- layer 1: h1^T = relu(W1fold * [nrm;dts] + Cfold) ----
        f16x acc;
        #pragma unroll
        for (int q = 0; q < 16; q++) acc[q] = Cf[q];
        acc = __builtin_amdgcn_mfma_f32_32x32x16_bf16(W1a, ndf, acc, 0, 0, 0);
        float h1[16];
        #pragma unroll
        for (int q = 0; q < 16; q++) h1[q] = fmaxf(acc[q], 0.f);

        // ---- layer 2: h2^T = relu(W2^T h1^T + b2) ----
        bf8 B0, B1;
        cswap(h1, half, B0, B1);
        #pragma unroll
        for (int q = 0; q < 16; q++) acc[q] = b2c[q];
        acc = __builtin_amdgcn_mfma_f32_32x32x16_bf16(W2a0, B0, acc, 0, 0, 0);
        acc = __builtin_amdgcn_mfma_f32_32x32x16_bf16(W2a1, B1, acc, 0, 0, 0);
        float h2[16];
        #pragma unroll
        for (int q = 0; q < 16; q++) h2[q] = fmaxf(acc[q], 0.f);

        // ---- gate: w = sigmoid(h2 . W5 + b5); m = h2 * w ----
        float zp = 0.f;
        #pragma unroll
        for (int q = 0; q < 16; q++) zp = fmaf(h2[q], W5c[q], zp);
        float z = zp + __shfl_xor(zp, 32) + b5v;
        float wgt = 1.f / (1.f + __expf(-z));
        float mm[16];
        #pragma unroll
        for (int q = 0; q < 16; q++) mm[q] = h2[q] * wgt;

        // ---- store m via LDS for coalescing (per-wave region, no barrier:
        //      DS ops of one wave execute in order) ----
        #pragma unroll
        for (int g = 0; g < 4; g++) {   // regs 4g..4g+3 = channels 8g+4*half+0..3
            *(float4*)&lds[n * 36 + 8 * g + 4 * half] =
                make_float4(mm[4 * g], mm[4 * g + 1], mm[4 * g + 2], mm[4 * g + 3]);
        }
        #pragma unroll
        for (int r = 0; r < 4; r++) {
            int fidx = r * 256 + lane * 4;         // flat f32 idx in [32][32]
            int edg = fidx >> 5, ch = fidx & 31;
            float4 v4 = *(const float4*)&lds[edg * 36 + ch];
            *(float4*)(m_out + (size_t)tile * 1024 + fidx) = v4;
        }

        // ---- layer 3 + phi_x head: phix = relu(m W3 + b3) . W4 ----
        bf8 M0, M1;
        cswap(mm, half, M0, M1);
        #pragma unroll
        for (int q = 0; q < 16; q++) acc[q] = b3c[q];
        acc = __builtin_amdgcn_mfma_f32_32x32x16_bf16(W3a0, M0, acc, 0, 0, 0);
        acc = __builtin_amdgcn_mfma_f32_32x32x16_bf16(W3a1, M1, acc, 0, 0, 0);
        float pp = 0.f;
        #pragma unroll
        for (int q = 0; q < 16; q++) pp = fmaf(fmaxf(acc[q], 0.f), W4c[q], pp);
        float phix = pp + __shfl_xor(pp, 32);

        float ux = fminf(fmaxf(dx * phix, -100.f), 100.f);
        float uy = fminf(fmaxf(dy * phix, -100.f), 100.f);
        float uz = fminf(fmaxf(dz * phix, -100.f), 100.f);
        if (half == 0) {
            atomicAdd(&sums[3 * i + 0], ux);
            atomicAdd(&sums[3 * i + 1], uy);
            atomicAdd(&sums[3 * i + 2], uz);
            atomicAdd(&counts[i], 1.f);
        }
    }
}

__global__ __launch_bounds__(256) void node_kernel(
    const float* __restrict__ x,
    const float* __restrict__ sums,
    const float* __restrict__ counts,
    float* __restrict__ out)
{
    int nn = blockIdx.x * blockDim.x + threadIdx.x;
    if (nn < NN) {
        float inv = 1.f / fmaxf(counts[nn], 1.f);
        out[3 * nn + 0] = x[3 * nn + 0] + sums[3 * nn + 0] * inv;
        out[3 * nn + 1] = x[3 * nn + 1] + sums[3 * nn + 1] * inv;
        out[3 * nn + 2] = x[3 * nn + 2] + sums[3 * nn + 2] * inv;
    }
}

extern "C" void kernel_launch(void* const* d_in, const int* in_sizes, int n_in,
                              void* d_out, int out_size, void* d_ws, size_t ws_size,
                              hipStream_t stream) {
    const float* x    = (const float*)d_in[0];
    const int*   ei   = (const int*)d_in[1];     // int32 per harness conversion
    const float* W1   = (const float*)d_in[2];
    const float* bn_g = (const float*)d_in[3];
    const float* bn_b = (const float*)d_in[4];
    const float* bn_m = (const float*)d_in[5];
    const float* bn_v = (const float*)d_in[6];
    const float* W2   = (const float*)d_in[7];
    const float* b2   = (const float*)d_in[8];
    const float* W3   = (const float*)d_in[9];
    const float* b3   = (const float*)d_in[10];
    const float* W4   = (const float*)d_in[11];
    const float* W5   = (const float*)d_in[12];
    const float* b5   = (const float*)d_in[13];

    float* out    = (float*)d_out;               // [x_tilde (3*NN) | m (NE*32)]
    float* m_out  = out + (size_t)3 * NN;
    float* sums   = (float*)d_ws;                // [3*NN]
    float* counts = sums + (size_t)3 * NN;       // [NN]

    hipMemsetAsync(d_ws, 0, (size_t)4 * NN * sizeof(float), stream);

    edge_kernel<<<EDGE_BLOCKS, 256, 0, stream>>>(
        x, ei, W1, bn_g, bn_b, bn_m, bn_v, W2, b2, W3, b3, W4, W5, b5,
        m_out, sums, counts);

    node_kernel<<<(NN + 255) / 256, 256, 0, stream>>>(x, sums, counts, out);
}